// Round 1
// 1671.879 us; speedup vs baseline: 1.6886x; 1.6886x over previous
//
#include <hip/hip_runtime.h>
#include <hip/hip_fp16.h>
#include <math.h>

#define HID  128
#define EDIM 416
#define CATD 672      // 2*HID + EDIM
#define NN   10000
#define NE   160000
#define EB   128      // edges per block (edge kernel)
#define NT   64       // nodes per block (node kernel)
#define KT   32       // K tile (node kernel)

typedef _Float16 f16x8 __attribute__((ext_vector_type(8)));
typedef float    f32x4 __attribute__((ext_vector_type(4)));

__device__ __forceinline__ float silu_f(float x) {
    return x / (1.0f + __expf(-x));
}

__device__ __forceinline__ unsigned int cvt2(float a, float b) {
    __half2 h = __floats2half2_rn(a, b);
    union { __half2 h2; unsigned int u; } c; c.h2 = h; return c.u;
}

// 16-B-granule XOR swizzle helpers.
// Tiles with 64-B rows (32 halves): granule ks in [0,4), swizzled by row bits.
__device__ __forceinline__ f16x8 frag32(const __half* base, int row, int ks) {
    return *reinterpret_cast<const f16x8*>(base + row * 32 + ((ks ^ ((row >> 1) & 3)) << 3));
}
// Tiles with 256-B rows (128 halves): granule g in [0,16).
__device__ __forceinline__ int swz128(int row, int g) { return (g & 8) | ((g ^ row) & 7); }
__device__ __forceinline__ f16x8 frag128(const __half* base, int row, int g) {
    return *reinterpret_cast<const f16x8*>(base + row * 128 + (swz128(row, g) << 3));
}

// ---------------- LayerNorm: one wave per node; emits fp32 + fp16 ----------------
__global__ __launch_bounds__(256) void ln_kernel(const float* __restrict__ x,
                                                 const float* __restrict__ g,
                                                 const float* __restrict__ b,
                                                 float* __restrict__ xh,
                                                 __half* __restrict__ xh_h) {
    int node = blockIdx.x * 4 + (threadIdx.x >> 6);
    int lane = threadIdx.x & 63;
    if (node >= NN) return;
    const float* xr = x + (size_t)node * HID;
    float v0 = xr[lane], v1 = xr[lane + 64];
    float s = v0 + v1;
    #pragma unroll
    for (int off = 1; off < 64; off <<= 1) s += __shfl_xor(s, off);
    float mu = s * (1.0f / HID);
    float d0 = v0 - mu, d1 = v1 - mu;
    float vs = d0 * d0 + d1 * d1;
    #pragma unroll
    for (int off = 1; off < 64; off <<= 1) vs += __shfl_xor(vs, off);
    float rstd = rsqrtf(vs * (1.0f / HID) + 1e-5f);
    float r0 = d0 * rstd * g[lane]      + b[lane];
    float r1 = d1 * rstd * g[lane + 64] + b[lane + 64];
    float* o = xh + (size_t)node * HID;
    o[lane] = r0; o[lane + 64] = r1;
    __half* oh = xh_h + (size_t)node * HID;
    oh[lane]      = __float2half(r0);
    oh[lane + 64] = __float2half(r1);
}

// ---------------- Weight pack: fp32 -> fp16, B-fragment order, swizzle baked in ---
// Granule (kt, col, ks) holds W[kt*32+ks*8+u][col], u=0..7, placed at
// col*32 + ((ks ^ ((col>>1)&3))<<3) halves within an 8 KB (or 2 KB) tile.
__global__ __launch_bounds__(256) void pack_kernel(
    const float* __restrict__ We1, const float* __restrict__ We2,
    const float* __restrict__ Wo,
    __half* __restrict__ We1p, __half* __restrict__ We2p, __half* __restrict__ Wop)
{
    int gid = blockIdx.x * 256 + threadIdx.x;
    if (gid < 10752) {                       // We1p: 21 tiles x 512 granules
        int kt = gid >> 9, r = gid & 511, col = r >> 2, kx = r & 3;
        __half* d = We1p + kt * 4096 + col * 32 + ((kx ^ ((col >> 1) & 3)) << 3);
        int k0 = kt * 32 + kx * 8;
        #pragma unroll
        for (int u = 0; u < 8; ++u) d[u] = __float2half(We1[(size_t)(k0 + u) * HID + col]);
    } else if (gid < 12800) {                // We2p: 4 tiles x 512
        int r2 = gid - 10752;
        int kt = r2 >> 9, r = r2 & 511, col = r >> 2, kx = r & 3;
        __half* d = We2p + kt * 4096 + col * 32 + ((kx ^ ((col >> 1) & 3)) << 3);
        int k0 = kt * 32 + kx * 8;
        #pragma unroll
        for (int u = 0; u < 8; ++u) d[u] = __float2half(We2[(size_t)(k0 + u) * HID + col]);
    } else if (gid < 18944) {                // Wop chunks 0..2: 3 x 4 tiles x 512
        int r3 = gid - 12800;
        int nc = r3 >> 11, r2 = r3 & 2047;
        int kt = r2 >> 9, r = r2 & 511, col = r >> 2, kx = r & 3;
        __half* d = Wop + nc * 16384 + kt * 4096 + col * 32 + ((kx ^ ((col >> 1) & 3)) << 3);
        int k0 = kt * 32 + kx * 8, cg = nc * 128 + col;
        #pragma unroll
        for (int u = 0; u < 8; ++u) d[u] = __float2half(Wo[(size_t)(k0 + u) * EDIM + cg]);
    } else if (gid < 19456) {                // Wop chunk 3 (cols 384..415): 4 tiles x 128
        int r3 = gid - 18944;
        int kt = r3 >> 7, r = r3 & 127, col = r >> 2, kx = r & 3;
        __half* d = Wop + 49152 + kt * 1024 + col * 32 + ((kx ^ ((col >> 1) & 3)) << 3);
        int k0 = kt * 32 + kx * 8, cg = 384 + col;
        #pragma unroll
        for (int u = 0; u < 8; ++u) d[u] = __float2half(Wo[(size_t)(k0 + u) * EDIM + cg]);
    }
}

// ---------------- Edge kernel: 128 edges/block, 4 waves (2x2), f16 MFMA ----------
__global__ __launch_bounds__(256, 2) void edge_kernel(
    const __half* __restrict__ xh_h,
    const float*  __restrict__ weight,
    const __half* __restrict__ We1p, const float* __restrict__ be1,
    const __half* __restrict__ We2p, const float* __restrict__ be2,
    const float*  __restrict__ Wa,   const float* __restrict__ ba,
    const __half* __restrict__ Wop,  const float* __restrict__ bo,
    const int* __restrict__ ii, const int* __restrict__ jj,
    float* __restrict__ agg, float* __restrict__ cnt,
    float* __restrict__ edgeh)
{
    __shared__ __half a1[EB * 32];        // 8 KB  A k-tile (64-B rows, swizzled)
    __shared__ __half bt[32 * 128];       // 8 KB  B k-tile (packed layout, linear copy)
    __shared__ __half ml[EB * 128];       // 32 KB m1 / m / m_ij (256-B rows, swizzled)
    __shared__ float  attv[EB];
    __shared__ float  Was[HID];
    __shared__ int    iis_s[EB], jjs_s[EB];

    const int t    = threadIdx.x;
    const int e0   = blockIdx.x * EB;
    const int lane = t & 63;
    const int w    = t >> 6;
    const int wr   = w >> 1, wc = w & 1;  // wave owns rows [wr*64,+64) x cols [wc*64,+64)
    const int li   = lane & 15, ks = lane >> 4;
    const int rb   = wr * 64, cb = wc * 64;

    if (t < EB) { iis_s[t] = ii[e0 + t]; jjs_s[t] = jj[e0 + t]; }
    if (t < HID) Was[t] = Wa[t];

    // ================= GEMM1: cat(672) @ We1 -> 128 =================
    f32x4 acc[4][4];
    #pragma unroll
    for (int fr = 0; fr < 4; ++fr)
        #pragma unroll
        for (int fc = 0; fc < 4; ++fc) {
            acc[fr][fc][0] = 0.f; acc[fr][fc][1] = 0.f;
            acc[fr][fc][2] = 0.f; acc[fr][fc][3] = 0.f;
        }

    #pragma unroll 1
    for (int kt = 0; kt < 21; ++kt) {
        __syncthreads();
        // stage A: 128 edges x 32 k. kt 0-3: xh[ii]; 4-7: xh[jj]; 8-20: weight (fp32->f16)
        #pragma unroll
        for (int q = 0; q < 2; ++q) {
            int gid = t + q * 256;
            int e = gid >> 2, kx = gid & 3;
            __half* dst = a1 + e * 32 + ((kx ^ ((e >> 1) & 3)) << 3);
            if (kt < 8) {
                int node = (kt < 4) ? iis_s[e] : jjs_s[e];
                *(uint4*)dst = *(const uint4*)(xh_h + (size_t)node * HID + (kt & 3) * 32 + kx * 8);
            } else {
                const float* s = weight + (size_t)(e0 + e) * EDIM + (kt - 8) * 32 + kx * 8;
                float4 f0 = *(const float4*)s;
                float4 f1 = *(const float4*)(s + 4);
                uint4 p;
                p.x = cvt2(f0.x, f0.y); p.y = cvt2(f0.z, f0.w);
                p.z = cvt2(f1.x, f1.y); p.w = cvt2(f1.z, f1.w);
                *(uint4*)dst = p;
            }
        }
        // stage B: linear copy of pre-packed 8 KB tile
        {
            const __half* bsrc = We1p + kt * 4096;
            uint4 v0 = *(const uint4*)(bsrc + t * 8);
            uint4 v1 = *(const uint4*)(bsrc + 2048 + t * 8);
            *(uint4*)(bt + t * 8) = v0;
            *(uint4*)(bt + 2048 + t * 8) = v1;
        }
        __syncthreads();
        f16x8 av[4], bv[4];
        #pragma unroll
        for (int fr = 0; fr < 4; ++fr) av[fr] = frag32(a1, rb + fr * 16 + li, ks);
        #pragma unroll
        for (int fc = 0; fc < 4; ++fc) bv[fc] = frag32(bt, cb + fc * 16 + li, ks);
        #pragma unroll
        for (int fr = 0; fr < 4; ++fr)
            #pragma unroll
            for (int fc = 0; fc < 4; ++fc)
                acc[fr][fc] = __builtin_amdgcn_mfma_f32_16x16x32_f16(av[fr], bv[fc], acc[fr][fc], 0, 0, 0);
    }
    // m1 = silu(acc + be1) -> ml (f16, swizzled granules)
    #pragma unroll
    for (int fc = 0; fc < 4; ++fc) {
        int c = cb + fc * 16 + li;
        float bias = be1[c];
        int gc = c >> 3;
        #pragma unroll
        for (int fr = 0; fr < 4; ++fr)
            #pragma unroll
            for (int bb = 0; bb < 4; ++bb) {
                int e = rb + fr * 16 + 4 * ks + bb;   // D row = 4*(lane>>4)+reg
                ml[e * 128 + (swz128(e, gc) << 3) + (c & 7)] =
                    __float2half(silu_f(acc[fr][fc][bb] + bias));
            }
    }

    // ================= GEMM2: m1(128) @ We2 -> 128 =================
    f32x4 acc2[4][4];
    #pragma unroll
    for (int fr = 0; fr < 4; ++fr)
        #pragma unroll
        for (int fc = 0; fc < 4; ++fc) {
            acc2[fr][fc][0] = 0.f; acc2[fr][fc][1] = 0.f;
            acc2[fr][fc][2] = 0.f; acc2[fr][fc][3] = 0.f;
        }
    #pragma unroll 1
    for (int kt = 0; kt < 4; ++kt) {
        __syncthreads();                       // guards ml writes (kt=0) + bt reuse
        {
            const __half* bsrc = We2p + kt * 4096;
            uint4 v0 = *(const uint4*)(bsrc + t * 8);
            uint4 v1 = *(const uint4*)(bsrc + 2048 + t * 8);
            *(uint4*)(bt + t * 8) = v0;
            *(uint4*)(bt + 2048 + t * 8) = v1;
        }
        __syncthreads();
        f16x8 av[4], bv[4];
        #pragma unroll
        for (int fr = 0; fr < 4; ++fr) av[fr] = frag128(ml, rb + fr * 16 + li, kt * 4 + ks);
        #pragma unroll
        for (int fc = 0; fc < 4; ++fc) bv[fc] = frag32(bt, cb + fc * 16 + li, ks);
        #pragma unroll
        for (int fr = 0; fr < 4; ++fr)
            #pragma unroll
            for (int fc = 0; fc < 4; ++fc)
                acc2[fr][fc] = __builtin_amdgcn_mfma_f32_16x16x32_f16(av[fr], bv[fc], acc2[fr][fc], 0, 0, 0);
    }
    __syncthreads();   // all reads of m1 complete before overwriting ml with m
    #pragma unroll
    for (int fc = 0; fc < 4; ++fc) {
        int c = cb + fc * 16 + li;
        float bias = be2[c];
        int gc = c >> 3;
        #pragma unroll
        for (int fr = 0; fr < 4; ++fr)
            #pragma unroll
            for (int bb = 0; bb < 4; ++bb) {
                int e = rb + fr * 16 + 4 * ks + bb;
                ml[e * 128 + (swz128(e, gc) << 3) + (c & 7)] =
                    __float2half(silu_f(acc2[fr][fc][bb] + bias));
            }
    }
    __syncthreads();

    // ================= attention: att = silu(m . Wa + ba) =================
    {
        int e = t >> 1, h = t & 1;
        float sum = 0.f;
        #pragma unroll
        for (int g8 = 0; g8 < 8; ++g8) {
            int g = h * 8 + g8;
            uint4 v = *(const uint4*)(ml + e * 128 + (swz128(e, g) << 3));
            const __half* hp = (const __half*)&v;
            #pragma unroll
            for (int u = 0; u < 8; ++u) sum += __half2float(hp[u]) * Was[g * 8 + u];
        }
        sum += __shfl_xor(sum, 1);
        if (h == 0) attv[e] = silu_f(sum + ba[0]);
    }
    __syncthreads();

    // ============ m_ij = m * att (in place) + mean-agg atomics ============
    {
        int e = t >> 1, h = t & 1;
        float atv = attv[e];
        __half2 a2 = __float2half2_rn(atv);
        int node = iis_s[e];
        float* aggrow = agg + (size_t)node * HID;
        #pragma unroll
        for (int g8 = 0; g8 < 8; ++g8) {
            int g = h * 8 + g8;
            uint4* p4 = (uint4*)(ml + e * 128 + (swz128(e, g) << 3));
            uint4 v = *p4;
            __half2* h2 = (__half2*)&v;
            #pragma unroll
            for (int i = 0; i < 4; ++i) h2[i] = __hmul2(h2[i], a2);
            *p4 = v;
            const __half* hp = (const __half*)&v;
            #pragma unroll
            for (int u = 0; u < 8; ++u)
                atomicAdd(aggrow + g * 8 + u, __half2float(hp[u]));
        }
        if (h == 0) atomicAdd(&cnt[node], 1.0f);
    }

    // ================= GEMM3: m_ij(128) @ Wo -> 416, epilogue =================
    #pragma unroll 1
    for (int nc = 0; nc < 3; ++nc) {          // col chunks 0..2 (128 cols each)
        f32x4 acc3[4][4];
        #pragma unroll
        for (int fr = 0; fr < 4; ++fr)
            #pragma unroll
            for (int fc = 0; fc < 4; ++fc) {
                acc3[fr][fc][0] = 0.f; acc3[fr][fc][1] = 0.f;
                acc3[fr][fc][2] = 0.f; acc3[fr][fc][3] = 0.f;
            }
        #pragma unroll 1
        for (int kt = 0; kt < 4; ++kt) {
            __syncthreads();
            {
                const __half* bsrc = Wop + nc * 16384 + kt * 4096;
                uint4 v0 = *(const uint4*)(bsrc + t * 8);
                uint4 v1 = *(const uint4*)(bsrc + 2048 + t * 8);
                *(uint4*)(bt + t * 8) = v0;
                *(uint4*)(bt + 2048 + t * 8) = v1;
            }
            __syncthreads();
            f16x8 av[4], bv[4];
            #pragma unroll
            for (int fr = 0; fr < 4; ++fr) av[fr] = frag128(ml, rb + fr * 16 + li, kt * 4 + ks);
            #pragma unroll
            for (int fc = 0; fc < 4; ++fc) bv[fc] = frag32(bt, cb + fc * 16 + li, ks);
            #pragma unroll
            for (int fr = 0; fr < 4; ++fr)
                #pragma unroll
                for (int fc = 0; fc < 4; ++fc)
                    acc3[fr][fc] = __builtin_amdgcn_mfma_f32_16x16x32_f16(av[fr], bv[fc], acc3[fr][fc], 0, 0, 0);
        }
        #pragma unroll
        for (int fc = 0; fc < 4; ++fc) {
            int cg = nc * 128 + cb + fc * 16 + li;
            float bias = bo[cg];
            #pragma unroll
            for (int fr = 0; fr < 4; ++fr)
                #pragma unroll
                for (int bb = 0; bb < 4; ++bb) {
                    int e = rb + fr * 16 + 4 * ks + bb;
                    size_t idx = (size_t)(e0 + e) * EDIM + cg;
                    edgeh[idx] = weight[idx] + silu_f(acc3[fr][fc][bb] + bias);
                }
        }
    }
    {                                         // chunk 3 (cols 384..415)
        f32x4 acc4[4];
        #pragma unroll
        for (int fr = 0; fr < 4; ++fr) {
            acc4[fr][0] = 0.f; acc4[fr][1] = 0.f; acc4[fr][2] = 0.f; acc4[fr][3] = 0.f;
        }
        #pragma unroll 1
        for (int kt = 0; kt < 4; ++kt) {
            __syncthreads();
            if (t < 128)
                *(uint4*)(bt + t * 8) = *(const uint4*)(Wop + 49152 + kt * 1024 + t * 8);
            __syncthreads();
            f16x8 av[4];
            #pragma unroll
            for (int fr = 0; fr < 4; ++fr) av[fr] = frag128(ml, rb + fr * 16 + li, kt * 4 + ks);
            f16x8 bv = frag32(bt, wc * 16 + li, ks);
            #pragma unroll
            for (int fr = 0; fr < 4; ++fr)
                acc4[fr] = __builtin_amdgcn_mfma_f32_16x16x32_f16(av[fr], bv, acc4[fr], 0, 0, 0);
        }
        int cg = 384 + wc * 16 + li;
        float bias = bo[cg];
        #pragma unroll
        for (int fr = 0; fr < 4; ++fr)
            #pragma unroll
            for (int bb = 0; bb < 4; ++bb) {
                int e = rb + fr * 16 + 4 * ks + bb;
                size_t idx = (size_t)(e0 + e) * EDIM + cg;
                edgeh[idx] = weight[idx] + silu_f(acc4[fr][bb] + bias);
            }
    }
}

// ---------------- Node kernel: 64 nodes x 128 outs per block (fp32, unchanged) ----
__global__ __launch_bounds__(256) void node_kernel(
    const float* __restrict__ xh,
    const float* __restrict__ agg, const float* __restrict__ cnt,
    const float* __restrict__ Wn1, const float* __restrict__ bn1,
    const float* __restrict__ Wn2, const float* __restrict__ bn2,
    float* __restrict__ out)
{
    __shared__ float catile[NT][KT + 1];
    __shared__ float wls[KT][HID];
    __shared__ float mls[NT][HID + 4];
    __shared__ float inv[NT];

    int t   = threadIdx.x;
    int n0b = blockIdx.x * NT;

    if (t < NT) {
        int n = n0b + t;
        float c = (n < NN) ? cnt[n] : 1.f;
        inv[t] = (c == 0.f) ? 1.f : 1.f / c;
    }

    int ec = t & 15, og = t >> 4, o0 = og * 8;

    float acc[4][8];
    #pragma unroll
    for (int r = 0; r < 4; ++r)
        #pragma unroll
        for (int c = 0; c < 8; ++c) acc[r][c] = 0.f;

    for (int kt = 0; kt < (2 * HID) / KT; ++kt) {
        int k0 = kt * KT;
        __syncthreads();
        #pragma unroll
        for (int j = 0; j < 8; ++j) {
            int idx = t + j * 256;
            int e = idx >> 5, k = idx & 31;
            int kk = k0 + k;
            int n = n0b + e;
            float v = 0.f;
            if (n < NN) {
                if (kk < HID) v = xh[(size_t)n * HID + kk];
                else          v = agg[(size_t)n * HID + (kk - HID)] * inv[e];
            }
            catile[e][k] = v;
        }
        #pragma unroll
        for (int j = 0; j < 16; ++j) {
            int idx = t + j * 256;
            int k = idx >> 7, o = idx & 127;
            wls[k][o] = Wn1[(size_t)(k0 + k) * HID + o];
        }
        __syncthreads();
        #pragma unroll
        for (int k = 0; k < KT; ++k) {
            float a[4], ww[8];
            #pragma unroll
            for (int r = 0; r < 4; ++r) a[r] = catile[ec + 16 * r][k];
            #pragma unroll
            for (int c = 0; c < 8; ++c) ww[c] = wls[k][o0 + c];
            #pragma unroll
            for (int r = 0; r < 4; ++r)
                #pragma unroll
                for (int c = 0; c < 8; ++c) acc[r][c] += a[r] * ww[c];
        }
    }
    {
        float bias[8];
        #pragma unroll
        for (int c = 0; c < 8; ++c) bias[c] = bn1[o0 + c];
        #pragma unroll
        for (int r = 0; r < 4; ++r)
            #pragma unroll
            for (int c = 0; c < 8; ++c)
                mls[ec + 16 * r][o0 + c] = silu_f(acc[r][c] + bias[c]);
    }

    float acc2[4][8];
    #pragma unroll
    for (int r = 0; r < 4; ++r)
        #pragma unroll
        for (int c = 0; c < 8; ++c) acc2[r][c] = 0.f;

    for (int kt = 0; kt < HID / KT; ++kt) {
        __syncthreads();
        #pragma unroll
        for (int j = 0; j < 16; ++j) {
            int idx = t + j * 256;
            int k = idx >> 7, o = idx & 127;
            wls[k][o] = Wn2[(size_t)(kt * KT + k) * HID + o];
        }
        __syncthreads();
        #pragma unroll
        for (int k = 0; k < KT; ++k) {
            float a[4], ww[8];
            #pragma unroll
            for (int r = 0; r < 4; ++r) a[r] = mls[ec + 16 * r][kt * KT + k];
            #pragma unroll
            for (int c = 0; c < 8; ++c) ww[c] = wls[k][o0 + c];
            #pragma unroll
            for (int r = 0; r < 4; ++r)
                #pragma unroll
                for (int c = 0; c < 8; ++c) acc2[r][c] += a[r] * ww[c];
        }
    }
    {
        float bias[8];
        #pragma unroll
        for (int c = 0; c < 8; ++c) bias[c] = bn2[o0 + c];
        #pragma unroll
        for (int r = 0; r < 4; ++r) {
            int n = n0b + ec + 16 * r;
            if (n < NN) {
                #pragma unroll
                for (int c = 0; c < 8; ++c)
                    out[(size_t)n * HID + o0 + c] =
                        xh[(size_t)n * HID + o0 + c] + silu_f(acc2[r][c] + bias[c]);
            }
        }
    }
}

extern "C" void kernel_launch(void* const* d_in, const int* in_sizes, int n_in,
                              void* d_out, int out_size, void* d_ws, size_t ws_size,
                              hipStream_t stream) {
    (void)in_sizes; (void)n_in; (void)out_size; (void)ws_size;
    const float* x      = (const float*)d_in[0];
    const float* weight = (const float*)d_in[1];
    const float* ln_g   = (const float*)d_in[2];
    const float* ln_b   = (const float*)d_in[3];
    const float* We1    = (const float*)d_in[4];
    const float* be1    = (const float*)d_in[5];
    const float* We2    = (const float*)d_in[6];
    const float* be2    = (const float*)d_in[7];
    const float* Wa     = (const float*)d_in[8];
    const float* ba     = (const float*)d_in[9];
    const float* Wn1    = (const float*)d_in[10];
    const float* bn1    = (const float*)d_in[11];
    const float* Wn2    = (const float*)d_in[12];
    const float* bn2    = (const float*)d_in[13];
    const float* Wo     = (const float*)d_in[14];
    const float* bo     = (const float*)d_in[15];
    const int*   eidx   = (const int*)d_in[16];
    const int* ii = eidx;
    const int* jj = eidx + NE;

    float*  xh   = (float*)d_ws;                 // 1,280,000 f
    float*  agg  = xh + (size_t)NN * HID;        // 1,280,000 f
    float*  cnt  = agg + (size_t)NN * HID;       // 10,000 f
    __half* xh_h = (__half*)(cnt + NN);          // 1,280,000 h
    __half* We1p = xh_h + (size_t)NN * HID;      // 86,016 h (21 tiles)
    __half* We2p = We1p + 86016;                 // 16,384 h (4 tiles)
    __half* Wop  = We2p + 16384;                 // 53,248 h (3x4 tiles + 4 small)

    float* xh_out = (float*)d_out;
    float* edgeh  = xh_out + (size_t)NN * HID;

    hipMemsetAsync(agg, 0, ((size_t)NN * HID + NN) * sizeof(float), stream);
    pack_kernel<<<76, 256, 0, stream>>>(We1, We2, Wo, We1p, We2p, Wop);
    ln_kernel<<<(NN + 3) / 4, 256, 0, stream>>>(x, ln_g, ln_b, xh, xh_h);
    edge_kernel<<<NE / EB, 256, 0, stream>>>(xh_h, weight, We1p, be1, We2p, be2,
                                             Wa, ba, Wop, bo, ii, jj,
                                             agg, cnt, edgeh);
    node_kernel<<<(NN + NT - 1) / NT, 256, 0, stream>>>(xh, agg, cnt,
                                                        Wn1, bn1, Wn2, bn2, xh_out);
}